// Round 9
// baseline (60.414 us; speedup 1.0000x reference)
//
#include <hip/hip_runtime.h>

// SeesawLoss forward, N=32768 rows, C=1203 classes (+2 binary logits).
// Round 9 = round 8 with the prep stage restructured (one edit):
//  - prep_k (single-block = single-CU serial node, ~5 us) REMOVED.
//  - hist: 32-block global-atomic histogram (int4 loads) after a 4.8 KB
//    memset node. Distributed, ~2 us.
//  - row kernel builds its own x4 shift-replicated P*log2(cum) table from
//    cum directly: 4.8 KB L2-resident reads/block (9.9 MB total vs round
//    8's 41 MB of 20 KB/block table staging) + ~5 transcendental logs per
//    thread. Same 20480 B LDS, same conflict-free 16B ds_read_b128 in the
//    hot loop, same math (fixed 2^-16 shift, analytic W bound, label
//    exclusion by subtraction), same __launch_bounds__(256) (no min-waves
//    clause -> no spill; round 7 proved (256,8) spills 87 MB/dispatch).
// 4 dispatches: memset, hist, row, reduce. No float/ordered atomics.

#define C_CLS   1203
#define ROW_LEN 1205
#define NBINS   1204
#define RPAD    1280
#define NEG_HUGE (-3.402823466e38f)
#define LOG2E    1.4426950408889634f
#define LN2      0.6931471805599453f
#define LOG_EPS2 (-6.643856189774724f)   // log2(0.01)
#define P_POW    0.8f
#define Q_POW    2.0f
#define M2FIX    16.0f                   // fixed softmax shift (|logits| << 11)

#if __has_builtin(__builtin_amdgcn_exp2f)
#define EXP2(x) __builtin_amdgcn_exp2f(x)
#else
#define EXP2(x) exp2f(x)
#endif
#if __has_builtin(__builtin_amdgcn_logf)
#define LOG2F_(x) __builtin_amdgcn_logf(x)
#else
#define LOG2F_(x) __log2f(x)
#endif

// ---------------- dispatch 2: distributed histogram ----------------
__launch_bounds__(256)
__global__ void hist_k(const int* __restrict__ labels, unsigned* __restrict__ cum, int N) {
    const int i = blockIdx.x * blockDim.x + threadIdx.x;
    const int nv = N >> 2;
    const int4* lp = (const int4*)labels;
    if (i < nv) {
        int4 v = lp[i];
        atomicAdd(&cum[v.x], 1u); atomicAdd(&cum[v.y], 1u);
        atomicAdd(&cum[v.z], 1u); atomicAdd(&cum[v.w], 1u);
    }
    if (blockIdx.x == 0 && (int)threadIdx.x < (N & 3))
        atomicAdd(&cum[labels[(N & ~3) + threadIdx.x]], 1u);
}

// ---------------- dispatch 3: per-row loss, one wave per row ----------------
__launch_bounds__(256)   // no min-waves clause: let VGPRs float, forbid spill
__global__ void seesaw_row_k(const float* __restrict__ cls,
                             const int* __restrict__ labels,
                             const float* __restrict__ lweights,
                             const unsigned* __restrict__ cum,
                             float* __restrict__ wsums,
                             int N) {
    __shared__ __align__(16) float plg[4][RPAD];   // 20480 B exactly

    // build the x4 shift-replicated table in-block: one log per entry,
    // 4 LDS writes (consecutive-bank, conflict-free). cum is 4.8 KB ->
    // L2-resident after the first blocks touch it.
    for (int j = threadIdx.x; j < RPAD + 3; j += 256) {
        float f = 0.0f;
        if (j < NBINS) f = P_POW * LOG2F_(fmaxf((float)cum[j], 1.0f));
        #pragma unroll
        for (int kk = 0; kk < 4; ++kk) {
            int u = j - kk;
            if (u >= 0 && u < RPAD) plg[kk][u] = f;
        }
    }
    __syncthreads();

    const int lane = threadIdx.x & 63;
    const int wv   = threadIdx.x >> 6;
    const int wid  = blockIdx.x * 4 + wv;
    const int nw   = gridDim.x * 4;        // multiple of 4 -> k wave-invariant

    float acc = 0.0f;
    int n = wid;
    if (n < N) {
        const int k = (-n) & 3;            // row base % 4 == n % 4 (1205%4==1)
        // scalar-only pipeline: labels/weights one row ahead (breaks the
        // labels[n] -> row[label] dependent-load chain; 2 registers)
        int   labc = labels[n];
        float wc   = lweights[n];

        for (;;) {
            const int  n2    = n + nw;
            const bool have2 = (n2 < N);
            int labn = 0; float wn = 0.0f;
            if (have2) { labn = labels[n2]; wn = lweights[n2]; }

            const float* row = cls + (size_t)n * ROW_LEN;
            const float labv = row[labc];
            const float c0   = row[C_CLS];
            const float c1   = row[C_CLS + 1];

            // ---- row load: prefix + 5 float4 segments (segs 0-3 pure classes)
            const float4* vp = (const float4*)(row + k);
            float4 q[5];
            #pragma unroll
            for (int i = 0; i < 4; ++i) q[i] = vp[(size_t)i * 64 + lane];
            {
                int b4 = k + 1024 + 4 * lane;
                float4 t = make_float4(NEG_HUGE, NEG_HUGE, NEG_HUGE, NEG_HUGE);
                if (b4 + 3 <= C_CLS - 1) {
                    t = vp[(size_t)256 + lane];
                } else {
                    if (b4     <= C_CLS - 1) t.x = row[b4];
                    if (b4 + 1 <= C_CLS - 1) t.y = row[b4 + 1];
                    if (b4 + 2 <= C_CLS - 1) t.z = row[b4 + 2];
                }
                q[4] = t;
            }
            float pv = (lane < k) ? row[lane] : NEG_HUGE;

            // ---- pass 1: log2 domain in place, s = sum 2^(xl - 16)
            // (no max pass: logits bounded, 2^(xl-16) can't overflow/vanish)
            pv *= LOG2E;
            float s = EXP2(pv - M2FIX);
            #pragma unroll
            for (int i = 0; i < 5; ++i) {
                q[i].x *= LOG2E; q[i].y *= LOG2E;
                q[i].z *= LOG2E; q[i].w *= LOG2E;
                s += EXP2(q[i].x - M2FIX) + EXP2(q[i].y - M2FIX)
                   + EXP2(q[i].z - M2FIX) + EXP2(q[i].w - M2FIX);
            }
            #pragma unroll
            for (int o = 32; o > 0; o >>= 1) s += __shfl_xor(s, o, 64);

            const float L2    = M2FIX + LOG2F_(s);
            const float labv2 = labv * LOG2E;
            const float G     = fmaxf(labv2, L2 + LOG_EPS2);  // L2 + logsm2
            const float W     = L2 + Q_POW * (L2 - G);        // >= max adj
            const float plogl = plg[0][labc];
            const float Wp    = W + plogl;
            const float mW    = -W;

            // ---- pass 2: T = sum 2^(adj - W); label term subtracted after
            // t = min(lg - Wp, -W) == min(lg - plogl, 0) - W
            float T;
            {
                float t = fminf(plg[0][lane] - Wp, mW);
                float h = fmaxf(pv - G, 0.0f);
                T = EXP2(fmaf(Q_POW, h, pv) + t);
            }
            #pragma unroll
            for (int i = 0; i < 5; ++i) {
                // 16B-aligned conflict-free ds_read_b128 for any k
                const float4 lg = *(const float4*)&plg[k][256 * i + 4 * lane];
                { float t = fminf(lg.x - Wp, mW), h = fmaxf(q[i].x - G, 0.f);
                  T += EXP2(fmaf(Q_POW, h, q[i].x) + t); }
                { float t = fminf(lg.y - Wp, mW), h = fmaxf(q[i].y - G, 0.f);
                  T += EXP2(fmaf(Q_POW, h, q[i].y) + t); }
                { float t = fminf(lg.z - Wp, mW), h = fmaxf(q[i].z - G, 0.f);
                  T += EXP2(fmaf(Q_POW, h, q[i].z) + t); }
                { float t = fminf(lg.w - Wp, mW), h = fmaxf(q[i].w - G, 0.f);
                  T += EXP2(fmaf(Q_POW, h, q[i].w) + t); }
            }
            #pragma unroll
            for (int o = 32; o > 0; o >>= 1) T += __shfl_xor(T, o, 64);
            T -= EXP2(labv2 - W);     // adj[label] == csc[label] exactly
            T = fmaxf(T, 1e-37f);

            // ---- per-row tail (wave-uniform)
            const float nl2 = W + LOG2F_(T);
            const float xx  = (nl2 - labv2) * LN2;
            const float rl  = (xx > 0.0f) ? (xx + log1pf(__expf(-xx)))
                                          : log1pf(__expf(xx));
            const float mm   = fmaxf(c0, c1);
            const float lseb = mm + __logf(__expf(c0 - mm) + __expf(c1 - mm));
            const float ce   = lseb - ((labc == C_CLS) ? c1 : c0);
            const float rlw  = (wc == 1.0f) ? rl : 0.0f;   // pos_mask == 1.0
            acc += rlw + ce * wc;

            if (!have2) break;
            n = n2; labc = labn; wc = wn;
        }
    }

    if (lane == 0) wsums[wid] = acc;   // per-wave partial, plain store
}

// ---------------- dispatch 4: deterministic final sum ----------------
__launch_bounds__(512)
__global__ void reduce_k(const float* __restrict__ wsums, int nb,
                         const int* __restrict__ avg_raw,
                         float* __restrict__ out) {
    int tid = threadIdx.x;
    float s = 0.0f;
    int nb4 = nb >> 2;
    const float4* bp = (const float4*)wsums;
    for (int i = tid; i < nb4; i += 512) {
        float4 v = bp[i];
        s += (v.x + v.y) + (v.z + v.w);
    }
    for (int i = (nb4 << 2) + tid; i < nb; i += 512) s += wsums[i];

    #pragma unroll
    for (int o = 32; o > 0; o >>= 1) s += __shfl_xor(s, o, 64);

    __shared__ float ws8[8];
    int lane = tid & 63, wvi = tid >> 6;
    if (lane == 0) ws8[wvi] = s;
    __syncthreads();
    if (tid == 0) {
        float t = 0.0f;
        #pragma unroll
        for (int i = 0; i < 8; ++i) t += ws8[i];
        int ai = avg_raw[0];
        float af;
        if (ai > 0 && ai < (1 << 26)) {
            af = (float)ai;              // stored as integer
        } else {
            union { int i; float f; } u; // stored as float bits
            u.i = ai;
            af = u.f;
        }
        out[0] = t / af;
    }
}

extern "C" void kernel_launch(void* const* d_in, const int* in_sizes, int n_in,
                              void* d_out, int out_size, void* d_ws, size_t ws_size,
                              hipStream_t stream) {
    const float* cls    = (const float*)d_in[0];
    const int*   labels = (const int*)d_in[1];
    const float* lw     = (const float*)d_in[2];
    const int*   avgp   = (const int*)d_in[3];
    float*       out    = (float*)d_out;

    const int N = in_sizes[1];

    // ws layout: [ unsigned cum[RPAD] | float wsums[g*4] ]
    unsigned* cum   = (unsigned*)d_ws;
    float*    wsums = (float*)d_ws + RPAD;

    int g = (N + 15) / 16;               // 4 waves/block * 4 rows/wave
    if (g > 2048) g = 2048;
    if (g < 1) g = 1;

    hipMemsetAsync(cum, 0, NBINS * sizeof(unsigned), stream);
    int hb = ((N >> 2) + 255) / 256;
    if (hb < 1) hb = 1;
    hist_k<<<hb, 256, 0, stream>>>(labels, cum, N);
    seesaw_row_k<<<g, 256, 0, stream>>>(cls, labels, lw, cum, wsums, N);
    reduce_k<<<1, 512, 0, stream>>>(wsums, g * 4, avgp, out);
}

// Round 10
// 48.307 us; speedup vs baseline: 1.2506x; 1.2506x over previous
//
#include <hip/hip_runtime.h>

// SeesawLoss forward, N=32768 rows, C=1203 classes (+2 binary logits).
// Round 10 = round-8 structure (1-block prep + row + reduce; measured 50.9)
// with ONE row-kernel change: the P*log2(cum) table values each lane needs
// are LOOP-INVARIANT (indices k+256i+4*lane, k wave-invariant since the
// grid stride is a multiple of 4) -> hoisted into 21 registers ONCE before
// the row loop. Hot loop has ZERO per-row LDS table reads except the
// wave-uniform plg[labc] broadcast (conflict-free by definition).
//  - LDS 20480 -> 5120 B (single-copy table; staging 41 MB -> 10 MB total)
//  - no x4 replication in prep_k
//  - __launch_bounds__(256) with NO min-waves clause (round 7: a (256,8)
//    cap spilled the row state, 87 MB/dispatch of scratch writes)
// 3 dispatches. No float atomics, no ordered atomics.

#define C_CLS   1203
#define ROW_LEN 1205
#define NBINS   1204
#define RPAD    1280
#define NEG_HUGE (-3.402823466e38f)
#define LOG2E    1.4426950408889634f
#define LN2      0.6931471805599453f
#define LOG_EPS2 (-6.643856189774724f)   // log2(0.01)
#define P_POW    0.8f
#define Q_POW    2.0f
#define M2FIX    16.0f                   // fixed softmax shift (|logits| << 11)

#if __has_builtin(__builtin_amdgcn_exp2f)
#define EXP2(x) __builtin_amdgcn_exp2f(x)
#else
#define EXP2(x) exp2f(x)
#endif
#if __has_builtin(__builtin_amdgcn_logf)
#define LOG2F_(x) __builtin_amdgcn_logf(x)
#else
#define LOG2F_(x) __log2f(x)
#endif

// ---------------- dispatch 1: histogram + single-copy P*log2(count) table ----
__launch_bounds__(1024)
__global__ void prep_k(const int* __restrict__ labels, int N,
                       float* __restrict__ plgG) {
    __shared__ unsigned hist[NBINS];
    for (int i = threadIdx.x; i < NBINS; i += 1024) hist[i] = 0u;
    __syncthreads();

    const int nv = N >> 2;
    const int4* lp = (const int4*)labels;
    for (int i = threadIdx.x; i < nv; i += 1024) {
        int4 v = lp[i];
        atomicAdd(&hist[v.x], 1u); atomicAdd(&hist[v.y], 1u);
        atomicAdd(&hist[v.z], 1u); atomicAdd(&hist[v.w], 1u);
    }
    for (int i = (N & ~3) + (int)threadIdx.x; i < N; i += 1024)
        atomicAdd(&hist[labels[i]], 1u);
    __syncthreads();

    for (int u = threadIdx.x; u < RPAD; u += 1024) {
        float v = 0.0f;
        if (u < NBINS) v = P_POW * LOG2F_(fmaxf((float)hist[u], 1.0f));
        plgG[u] = v;     // pad region = 0 (masked elements are -inf in q)
    }
}

// ---------------- dispatch 2: per-row loss, one wave per row ----------------
__launch_bounds__(256)   // no min-waves clause: let VGPRs float, forbid spill
__global__ void seesaw_row_k(const float* __restrict__ cls,
                             const int* __restrict__ labels,
                             const float* __restrict__ lweights,
                             const float* __restrict__ plgG,
                             float* __restrict__ wsums,
                             int N) {
    __shared__ __align__(16) float plg[RPAD];   // 5120 B single copy
    {
        const float4* src = (const float4*)plgG;
        float4* dst = (float4*)plg;
        for (int i = threadIdx.x; i < RPAD / 4; i += 256) dst[i] = src[i];
    }
    __syncthreads();

    const int lane = threadIdx.x & 63;
    const int wv   = threadIdx.x >> 6;
    const int wid  = blockIdx.x * 4 + wv;
    const int nw   = gridDim.x * 4;        // multiple of 4 -> k wave-invariant

    float acc = 0.0f;
    int n = wid;
    if (n < N) {
        const int k = (-n) & 3;            // row base % 4 == n % 4 (1205%4==1)

        // ---- hoist the lane's 21 loop-invariant table values to registers
        // (one-time scalar LDS reads; conflicts here are a one-off, ~nothing)
        const float lgp = plg[lane];       // prefix entry (lanes < k use it)
        float4 lgr[5];
        #pragma unroll
        for (int i = 0; i < 5; ++i) {
            const int u = k + 256 * i + 4 * lane;
            lgr[i].x = plg[u];     lgr[i].y = plg[u + 1];
            lgr[i].z = plg[u + 2]; lgr[i].w = plg[u + 3];
        }

        // scalar-only pipeline: labels/weights one row ahead
        int   labc = labels[n];
        float wc   = lweights[n];

        for (;;) {
            const int  n2    = n + nw;
            const bool have2 = (n2 < N);
            int labn = 0; float wn = 0.0f;
            if (have2) { labn = labels[n2]; wn = lweights[n2]; }

            const float* row = cls + (size_t)n * ROW_LEN;
            const float labv = row[labc];
            const float c0   = row[C_CLS];
            const float c1   = row[C_CLS + 1];

            // ---- row load: prefix + 5 float4 segments (segs 0-3 pure classes)
            const float4* vp = (const float4*)(row + k);
            float4 q[5];
            #pragma unroll
            for (int i = 0; i < 4; ++i) q[i] = vp[(size_t)i * 64 + lane];
            {
                int b4 = k + 1024 + 4 * lane;
                float4 t = make_float4(NEG_HUGE, NEG_HUGE, NEG_HUGE, NEG_HUGE);
                if (b4 + 3 <= C_CLS - 1) {
                    t = vp[(size_t)256 + lane];
                } else {
                    if (b4     <= C_CLS - 1) t.x = row[b4];
                    if (b4 + 1 <= C_CLS - 1) t.y = row[b4 + 1];
                    if (b4 + 2 <= C_CLS - 1) t.z = row[b4 + 2];
                }
                q[4] = t;
            }
            float pv = (lane < k) ? row[lane] : NEG_HUGE;

            // ---- pass 1: log2 domain in place, s = sum 2^(xl - 16)
            pv *= LOG2E;
            float s = EXP2(pv - M2FIX);
            #pragma unroll
            for (int i = 0; i < 5; ++i) {
                q[i].x *= LOG2E; q[i].y *= LOG2E;
                q[i].z *= LOG2E; q[i].w *= LOG2E;
                s += EXP2(q[i].x - M2FIX) + EXP2(q[i].y - M2FIX)
                   + EXP2(q[i].z - M2FIX) + EXP2(q[i].w - M2FIX);
            }
            #pragma unroll
            for (int o = 32; o > 0; o >>= 1) s += __shfl_xor(s, o, 64);

            const float L2    = M2FIX + LOG2F_(s);
            const float labv2 = labv * LOG2E;
            const float G     = fmaxf(labv2, L2 + LOG_EPS2);  // L2 + logsm2
            const float W     = L2 + Q_POW * (L2 - G);        // >= max adj
            const float plogl = plg[labc];   // wave-uniform -> LDS broadcast
            const float Wp    = W + plogl;
            const float mW    = -W;

            // ---- pass 2: T = sum 2^(adj - W); label term subtracted after
            // t = min(lg - Wp, -W) == min(lg - plogl, 0) - W
            float T;
            {
                float t = fminf(lgp - Wp, mW);
                float h = fmaxf(pv - G, 0.0f);
                T = EXP2(fmaf(Q_POW, h, pv) + t);
            }
            #pragma unroll
            for (int i = 0; i < 5; ++i) {
                { float t = fminf(lgr[i].x - Wp, mW), h = fmaxf(q[i].x - G, 0.f);
                  T += EXP2(fmaf(Q_POW, h, q[i].x) + t); }
                { float t = fminf(lgr[i].y - Wp, mW), h = fmaxf(q[i].y - G, 0.f);
                  T += EXP2(fmaf(Q_POW, h, q[i].y) + t); }
                { float t = fminf(lgr[i].z - Wp, mW), h = fmaxf(q[i].z - G, 0.f);
                  T += EXP2(fmaf(Q_POW, h, q[i].z) + t); }
                { float t = fminf(lgr[i].w - Wp, mW), h = fmaxf(q[i].w - G, 0.f);
                  T += EXP2(fmaf(Q_POW, h, q[i].w) + t); }
            }
            #pragma unroll
            for (int o = 32; o > 0; o >>= 1) T += __shfl_xor(T, o, 64);
            T -= EXP2(labv2 - W);     // adj[label] == csc[label] exactly
            T = fmaxf(T, 1e-37f);

            // ---- per-row tail (wave-uniform)
            const float nl2 = W + LOG2F_(T);
            const float xx  = (nl2 - labv2) * LN2;
            const float rl  = (xx > 0.0f) ? (xx + log1pf(__expf(-xx)))
                                          : log1pf(__expf(xx));
            const float mm   = fmaxf(c0, c1);
            const float lseb = mm + __logf(__expf(c0 - mm) + __expf(c1 - mm));
            const float ce   = lseb - ((labc == C_CLS) ? c1 : c0);
            const float rlw  = (wc == 1.0f) ? rl : 0.0f;   // pos_mask == 1.0
            acc += rlw + ce * wc;

            if (!have2) break;
            n = n2; labc = labn; wc = wn;
        }
    }

    if (lane == 0) wsums[wid] = acc;   // per-wave partial, plain store
}

// ---------------- dispatch 3: deterministic final sum ----------------
__launch_bounds__(512)
__global__ void reduce_k(const float* __restrict__ wsums, int nb,
                         const int* __restrict__ avg_raw,
                         float* __restrict__ out) {
    int tid = threadIdx.x;
    float s = 0.0f;
    int nb4 = nb >> 2;
    const float4* bp = (const float4*)wsums;
    for (int i = tid; i < nb4; i += 512) {
        float4 v = bp[i];
        s += (v.x + v.y) + (v.z + v.w);
    }
    for (int i = (nb4 << 2) + tid; i < nb; i += 512) s += wsums[i];

    #pragma unroll
    for (int o = 32; o > 0; o >>= 1) s += __shfl_xor(s, o, 64);

    __shared__ float ws8[8];
    int lane = tid & 63, wvi = tid >> 6;
    if (lane == 0) ws8[wvi] = s;
    __syncthreads();
    if (tid == 0) {
        float t = 0.0f;
        #pragma unroll
        for (int i = 0; i < 8; ++i) t += ws8[i];
        int ai = avg_raw[0];
        float af;
        if (ai > 0 && ai < (1 << 26)) {
            af = (float)ai;              // stored as integer
        } else {
            union { int i; float f; } u; // stored as float bits
            u.i = ai;
            af = u.f;
        }
        out[0] = t / af;
    }
}

extern "C" void kernel_launch(void* const* d_in, const int* in_sizes, int n_in,
                              void* d_out, int out_size, void* d_ws, size_t ws_size,
                              hipStream_t stream) {
    const float* cls    = (const float*)d_in[0];
    const int*   labels = (const int*)d_in[1];
    const float* lw     = (const float*)d_in[2];
    const int*   avgp   = (const int*)d_in[3];
    float*       out    = (float*)d_out;

    const int N = in_sizes[1];

    // ws layout: [ float plgG[RPAD] | float wsums[g*4] ]
    float* plgG  = (float*)d_ws;
    float* wsums = (float*)d_ws + RPAD;

    int g = (N + 15) / 16;               // 4 waves/block * 4 rows/wave
    if (g > 2048) g = 2048;
    if (g < 1) g = 1;

    prep_k<<<1, 1024, 0, stream>>>(labels, N, plgG);
    seesaw_row_k<<<g, 256, 0, stream>>>(cls, labels, lw, plgG, wsums, N);
    reduce_k<<<1, 512, 0, stream>>>(wsums, g * 4, avgp, out);
}